// Round 7
// baseline (65.837 us; speedup 1.0000x reference)
//
#include <hip/hip_runtime.h>
#include <hip/hip_bf16.h>

// Sizes fixed by setup_inputs()
#define N_EL   1024
#define N_UP   512
#define NNUC   256
#define DIM    256
#define EDIM   32

#define GAIN_F      1.7872135f          // 1/std(silu(N(0,1))), analytic
#define INV_SQRT2_F 0.7071067811865476f

typedef __attribute__((ext_vector_type(8))) short bf16x8;
typedef __attribute__((ext_vector_type(4))) short bf16x4;
typedef __attribute__((ext_vector_type(4))) float f32x4;

__device__ __forceinline__ short f2bf(float x) {
    union { __hip_bfloat16 h; short s; } u;
    u.h = __float2bfloat16(x);     // compiler pk-fuses pairs (v_cvt_pk_bf16_f32)
    return u.s;
}

// ---------------------------------------------------------------------------
// K0 prep: layout rearrangement + f32->bf16 conversion (identical to R6).
// ---------------------------------------------------------------------------
__global__ __launch_bounds__(256) void prep_kernel(
    const float* __restrict__ up, const float* __restrict__ dn,
    const float* __restrict__ wedge,
    const float* __restrict__ w1, const float* __restrict__ w2,
    const float* __restrict__ elec,
    float* __restrict__ tab_up, float* __restrict__ tab_dn,
    short* __restrict__ wedge_arr,
    short* __restrict__ w1f, short* __restrict__ w2f,
    short* __restrict__ elecb)
{
    const int idx = (blockIdx.x << 8) + threadIdx.x;   // 0..65535

    { // spin tables -> C-fragment order (f32)
        const int kt = idx >> 12;
        const int dt = (idx >> 8) & 15;
        const int l  = (idx >> 2) & 63;
        const int r  = idx & 3;
        const int row = (kt << 4) + ((l >> 4) << 2) + r;
        const int col = (dt << 4) + (l & 15);
        tab_up[idx] = up[row * DIM + col];
        tab_dn[idx] = dn[row * DIM + col];
    }
    if (idx < 16 * 64 * 8) {                           // W_edge B-frag (8192)
        const int dt2 = idx >> 9;
        const int l2  = (idx >> 3) & 63;
        const int b   = idx & 7;
        const int j   = ((l2 >> 4) << 3) + b;
        const int d   = (dt2 << 4) + (l2 & 15);
        wedge_arr[idx] = f2bf(wedge[j * DIM + d]);
    }
    { // W1/W2 -> B-frag bf16 (65536 each)
        const int b  = idx & 7;
        const int l  = (idx >> 3) & 63;
        const int q  = (idx >> 9) & 7;
        const int nt = idx >> 12;
        const int j  = (q << 5) + ((l >> 4) << 3) + b;
        const int d  = (nt << 4) + (l & 15);
        w1f[idx] = f2bf(w1[j * DIM + d]);
        w2f[idx] = f2bf(w2[j * DIM + d]);
    }
    { // elec -> row-major bf16, 4 elems/thread
        const f32x4 v = *(const f32x4*)(elec + (idx << 2));
        bf16x4 o;
        o[0] = f2bf(v[0]); o[1] = f2bf(v[1]); o[2] = f2bf(v[2]); o[3] = f2bf(v[3]);
        *(bf16x4*)(elecb + (idx << 2)) = o;
    }
}

// ---------------------------------------------------------------------------
// K1 edge: fused edge-GEMM * spin-table * segment-sum (identical to R6).
// ---------------------------------------------------------------------------
__global__ __launch_bounds__(256) void edge_kernel(
    const float* __restrict__ eemb,
    const float* __restrict__ tab_up, const float* __restrict__ tab_dn,
    const short* __restrict__ wedge_arr,
    const float* __restrict__ s1p,
    float* __restrict__ agg)
{
    __shared__ float part[4][4][256];      // [wave][e][d]
    const int tid  = threadIdx.x;
    const int w    = tid >> 6;
    const int lane = tid & 63;
    const int g    = lane >> 4;
    const int c    = lane & 15;
    const int base = blockIdx.x << 2;
    const float* __restrict__ tab = (base < N_UP) ? tab_up : tab_dn;

    bf16x8 a[4][4];
    #pragma unroll
    for (int e = 0; e < 4; ++e) {
        #pragma unroll
        for (int q = 0; q < 4; ++q) {
            const int kt = (w << 2) + q;
            const float* src = eemb +
                ((size_t)((base + e) * NNUC + (kt << 4) + c) * EDIM + (g << 3));
            f32x4 lo = *(const f32x4*)(src);
            f32x4 hi = *(const f32x4*)(src + 4);
            union { bf16x8 v; short s[8]; } f;
            f.s[0] = f2bf(lo[0]); f.s[1] = f2bf(lo[1]);
            f.s[2] = f2bf(lo[2]); f.s[3] = f2bf(lo[3]);
            f.s[4] = f2bf(hi[0]); f.s[5] = f2bf(hi[1]);
            f.s[6] = f2bf(hi[2]); f.s[7] = f2bf(hi[3]);
            a[e][q] = f.v;
        }
    }

    const int kt0 = (w << 2);
    bf16x8 bnxt = *(const bf16x8*)(wedge_arr + (lane << 3));           // dt=0
    f32x4 tn0, tn1, tn2, tn3;
    tn0 = *(const f32x4*)(tab + ((((kt0 + 0) << 4) + 0) * 64 + lane) * 4);
    tn1 = *(const f32x4*)(tab + ((((kt0 + 1) << 4) + 0) * 64 + lane) * 4);
    tn2 = *(const f32x4*)(tab + ((((kt0 + 2) << 4) + 0) * 64 + lane) * 4);
    tn3 = *(const f32x4*)(tab + ((((kt0 + 3) << 4) + 0) * 64 + lane) * 4);

    const f32x4 zero4 = {0.f, 0.f, 0.f, 0.f};

    #pragma unroll 1
    for (int dt = 0; dt < 16; ++dt) {
        const bf16x8 bcur = bnxt;
        const f32x4 t0 = tn0, t1 = tn1, t2 = tn2, t3 = tn3;
        if (dt < 15) {
            bnxt = *(const bf16x8*)(wedge_arr + (((dt + 1) << 6) + lane) * 8);
            tn0 = *(const f32x4*)(tab + ((((kt0 + 0) << 4) + dt + 1) * 64 + lane) * 4);
            tn1 = *(const f32x4*)(tab + ((((kt0 + 1) << 4) + dt + 1) * 64 + lane) * 4);
            tn2 = *(const f32x4*)(tab + ((((kt0 + 2) << 4) + dt + 1) * 64 + lane) * 4);
            tn3 = *(const f32x4*)(tab + ((((kt0 + 3) << 4) + dt + 1) * 64 + lane) * 4);
        }
        float p[4] = {0.f, 0.f, 0.f, 0.f};
        #pragma unroll
        for (int e = 0; e < 4; ++e) {
            f32x4 cc;
            cc = __builtin_amdgcn_mfma_f32_16x16x32_bf16(a[e][0], bcur, zero4, 0, 0, 0);
            p[e] += cc[0] * t0[0] + cc[1] * t0[1] + cc[2] * t0[2] + cc[3] * t0[3];
            cc = __builtin_amdgcn_mfma_f32_16x16x32_bf16(a[e][1], bcur, zero4, 0, 0, 0);
            p[e] += cc[0] * t1[0] + cc[1] * t1[1] + cc[2] * t1[2] + cc[3] * t1[3];
            cc = __builtin_amdgcn_mfma_f32_16x16x32_bf16(a[e][2], bcur, zero4, 0, 0, 0);
            p[e] += cc[0] * t2[0] + cc[1] * t2[1] + cc[2] * t2[2] + cc[3] * t2[3];
            cc = __builtin_amdgcn_mfma_f32_16x16x32_bf16(a[e][3], bcur, zero4, 0, 0, 0);
            p[e] += cc[0] * t3[0] + cc[1] * t3[1] + cc[2] * t3[2] + cc[3] * t3[3];
        }
        #pragma unroll
        for (int e = 0; e < 4; ++e) {
            float v = p[e];
            v += __shfl_xor(v, 16, 64);
            v += __shfl_xor(v, 32, 64);
            if (lane < 16) part[w][e][(dt << 4) + lane] = v;
        }
    }
    __syncthreads();

    const float s1 = *s1p;
    for (int t = tid; t < 4 * 256; t += 256) {
        const int e = t >> 8;
        const int d = t & 255;
        const float s = part[0][e][d] + part[1][e][d] +
                        part[2][e][d] + part[3][e][d];
        agg[(size_t)(base + e) * DIM + d] = s * s1;
    }
}

// ---------------------------------------------------------------------------
// K2 out: gemm1+gemm2 tiled GEMM chain (identical to R6).
// ---------------------------------------------------------------------------
__global__ __launch_bounds__(512) void out_kernel(
    const short* __restrict__ elecb,
    const short* __restrict__ w1f, const short* __restrict__ w2f,
    const float* __restrict__ elec, const float* __restrict__ agg,
    const float* __restrict__ norm,
    const float* __restrict__ b1, const float* __restrict__ b2,
    const float* __restrict__ s2p,
    float* __restrict__ outp)
{
    __shared__ short h_s[16][264];      // +8 pad -> 2-way banks (free)

    const int tid  = threadIdx.x;
    const int w    = tid >> 6;          // 0..7
    const int lane = tid & 63;
    const int g    = lane >> 4;
    const int c    = lane & 15;
    const int mb   = blockIdx.x << 4;   // 16 rows per block

    const short* abase = elecb + ((mb + c) << 8) + (g << 3);
    bf16x8 a[8];
    #pragma unroll
    for (int q = 0; q < 8; ++q) a[q] = *(const bf16x8*)(abase + (q << 5));

    const float s2 = *s2p;

    // ---------------- gemm1 ----------------
    #pragma unroll
    for (int t = 0; t < 2; ++t) {
        const int ct = (w << 1) + t;
        const short* bb = w1f + (ct << 12) + (lane << 3);
        bf16x8 b[8];
        #pragma unroll
        for (int q = 0; q < 8; ++q) b[q] = *(const bf16x8*)(bb + (q << 9));
        f32x4 acc = {0.f, 0.f, 0.f, 0.f};
        #pragma unroll
        for (int q = 0; q < 8; ++q)
            acc = __builtin_amdgcn_mfma_f32_16x16x32_bf16(a[q], b[q], acc, 0, 0, 0);

        const int n  = (ct << 4) + c;
        const float bv = b1[n];
        #pragma unroll
        for (int r = 0; r < 4; ++r) {
            const int mr = (g << 2) + r;            // 0..15 (C-frag row)
            const int m  = mb + mr;
            const float y = (acc[r] + bv + agg[(m << 8) + n] * norm[m]) * s2;
            const float sig = 1.f / (1.f + __expf(-y));
            h_s[mr][n] = f2bf(GAIN_F * y * sig);
        }
    }
    __syncthreads();

    // ---------------- gemm2 ----------------
    bf16x8 a2[8];                                   // row = c, k = q*32+g*8+b
    #pragma unroll
    for (int q = 0; q < 8; ++q)
        a2[q] = *(const bf16x8*)(&h_s[c][(q << 5) + (g << 3)]);

    #pragma unroll
    for (int t = 0; t < 2; ++t) {
        const int ct = (w << 1) + t;
        const short* bb = w2f + (ct << 12) + (lane << 3);
        bf16x8 b[8];
        #pragma unroll
        for (int q = 0; q < 8; ++q) b[q] = *(const bf16x8*)(bb + (q << 9));
        f32x4 acc = {0.f, 0.f, 0.f, 0.f};
        #pragma unroll
        for (int q = 0; q < 8; ++q)
            acc = __builtin_amdgcn_mfma_f32_16x16x32_bf16(a2[q], b[q], acc, 0, 0, 0);

        const int n  = (ct << 4) + c;
        const float bv = b2[n];
        #pragma unroll
        for (int r = 0; r < 4; ++r) {
            const int m = mb + (g << 2) + r;
            const float z = acc[r] + bv;
            const float sig = 1.f / (1.f + __expf(-z));
            const float o = GAIN_F * z * sig;
            outp[(m << 8) + n] = (elec[(m << 8) + n] + o) * INV_SQRT2_F;
        }
    }
}

// ---------------------------------------------------------------------------
// MEASUREMENT ROUND: the full pipeline is launched TWICE per call.
// All kernels are pure functions of d_in (ws fully rewritten each pass),
// so the second pass recomputes identical values -> output unchanged.
// dur_R7 - dur_R6 = warm cost of one full (prep+edge+out) pass.
// ---------------------------------------------------------------------------
extern "C" void kernel_launch(void* const* d_in, const int* in_sizes, int n_in,
                              void* d_out, int out_size, void* d_ws, size_t ws_size,
                              hipStream_t stream)
{
    const float* elec  = (const float*)d_in[0];
    const float* up    = (const float*)d_in[1];
    const float* dn    = (const float*)d_in[2];
    const float* eemb  = (const float*)d_in[3];
    // d_in[4] = contr: init-time only, unused at runtime
    const float* norm  = (const float*)d_in[5];
    const float* W1    = (const float*)d_in[6];
    const float* b1    = (const float*)d_in[7];
    const float* Wedge = (const float*)d_in[8];
    const float* W2    = (const float*)d_in[9];
    const float* b2    = (const float*)d_in[10];
    const float* s1    = (const float*)d_in[11];
    const float* s2    = (const float*)d_in[12];

    // ws layout: tab_up 65536 f32 | tab_dn 65536 f32 | shorts:
    //   wedge_arr 8192 | w1f 65536 | w2f 65536 | elecb 262144 | agg (f32) 262144
    float* ws     = (float*)d_ws;
    float* tab_up = ws;
    float* tab_dn = ws + 65536;
    short* sbase  = (short*)(ws + 131072);
    short* warr   = sbase;
    short* w1f    = sbase + 8192;
    short* w2f    = sbase + 8192 + 65536;
    short* elecb  = sbase + 8192 + 131072;
    float* agg    = (float*)(sbase + 8192 + 131072 + 262144);

    for (int pass = 0; pass < 2; ++pass) {
        prep_kernel<<<256, 256, 0, stream>>>(up, dn, Wedge, W1, W2, elec,
                                             tab_up, tab_dn, warr, w1f, w2f, elecb);
        edge_kernel<<<256, 256, 0, stream>>>(eemb, tab_up, tab_dn, warr, s1, agg);
        out_kernel <<<64, 512, 0, stream>>>(elecb, w1f, w2f, elec, agg, norm,
                                            b1, b2, s2, (float*)d_out);
    }
}

// Round 8
// 32.328 us; speedup vs baseline: 2.0365x; 2.0365x over previous
//
#include <hip/hip_runtime.h>
#include <hip/hip_bf16.h>

// Sizes fixed by setup_inputs()
#define N_EL   1024
#define N_UP   512
#define NNUC   256
#define DIM    256
#define EDIM   32

#define GAIN_F      1.7872135f          // 1/std(silu(N(0,1))), analytic
#define INV_SQRT2_F 0.7071067811865476f

typedef __attribute__((ext_vector_type(8))) short bf16x8;
typedef __attribute__((ext_vector_type(4))) short bf16x4;
typedef __attribute__((ext_vector_type(4))) float f32x4;

__device__ __forceinline__ short f2bf(float x) {
    union { __hip_bfloat16 h; short s; } u;
    u.h = __float2bfloat16(x);     // compiler pk-fuses pairs (v_cvt_pk_bf16_f32)
    return u.s;
}

// ---------------------------------------------------------------------------
// K0 prep: layout rearrangement + f32->bf16 conversion (identical to R6).
// ---------------------------------------------------------------------------
__global__ __launch_bounds__(256) void prep_kernel(
    const float* __restrict__ up, const float* __restrict__ dn,
    const float* __restrict__ wedge,
    const float* __restrict__ w1, const float* __restrict__ w2,
    const float* __restrict__ elec,
    float* __restrict__ tab_up, float* __restrict__ tab_dn,
    short* __restrict__ wedge_arr,
    short* __restrict__ w1f, short* __restrict__ w2f,
    short* __restrict__ elecb)
{
    const int idx = (blockIdx.x << 8) + threadIdx.x;   // 0..65535

    { // spin tables -> C-fragment order (f32)
        const int kt = idx >> 12;
        const int dt = (idx >> 8) & 15;
        const int l  = (idx >> 2) & 63;
        const int r  = idx & 3;
        const int row = (kt << 4) + ((l >> 4) << 2) + r;
        const int col = (dt << 4) + (l & 15);
        tab_up[idx] = up[row * DIM + col];
        tab_dn[idx] = dn[row * DIM + col];
    }
    if (idx < 16 * 64 * 8) {                           // W_edge B-frag (8192)
        const int dt2 = idx >> 9;
        const int l2  = (idx >> 3) & 63;
        const int b   = idx & 7;
        const int j   = ((l2 >> 4) << 3) + b;
        const int d   = (dt2 << 4) + (l2 & 15);
        wedge_arr[idx] = f2bf(wedge[j * DIM + d]);
    }
    { // W1/W2 -> B-frag bf16 (65536 each)
        const int b  = idx & 7;
        const int l  = (idx >> 3) & 63;
        const int q  = (idx >> 9) & 7;
        const int nt = idx >> 12;
        const int j  = (q << 5) + ((l >> 4) << 3) + b;
        const int d  = (nt << 4) + (l & 15);
        w1f[idx] = f2bf(w1[j * DIM + d]);
        w2f[idx] = f2bf(w2[j * DIM + d]);
    }
    { // elec -> row-major bf16, 4 elems/thread
        const f32x4 v = *(const f32x4*)(elec + (idx << 2));
        bf16x4 o;
        o[0] = f2bf(v[0]); o[1] = f2bf(v[1]); o[2] = f2bf(v[2]); o[3] = f2bf(v[3]);
        *(bf16x4*)(elecb + (idx << 2)) = o;
    }
}

// ---------------------------------------------------------------------------
// K1 edge (R8 latency package): 512 blocks x 2 electrons (2 blocks/CU ->
// 2 waves/SIMD) + 3-deep rotating tab/wedge prefetch (fully unrolled,
// compile-time slots). Math identical to R6.
// ---------------------------------------------------------------------------
__global__ __launch_bounds__(256) void edge_kernel(
    const float* __restrict__ eemb,
    const float* __restrict__ tab_up, const float* __restrict__ tab_dn,
    const short* __restrict__ wedge_arr,
    const float* __restrict__ s1p,
    float* __restrict__ agg)
{
    __shared__ float part[4][2][256];      // [wave][e][d]  8 KB
    const int tid  = threadIdx.x;
    const int w    = tid >> 6;
    const int lane = tid & 63;
    const int g    = lane >> 4;
    const int c    = lane & 15;
    const int base = blockIdx.x << 1;      // 2 electrons per block
    const float* __restrict__ tab = (base < N_UP) ? tab_up : tab_dn;

    // A fragments: 2 electrons x 4 k-tiles
    bf16x8 a[2][4];
    #pragma unroll
    for (int e = 0; e < 2; ++e) {
        #pragma unroll
        for (int q = 0; q < 4; ++q) {
            const int kt = (w << 2) + q;
            const float* src = eemb +
                ((size_t)((base + e) * NNUC + (kt << 4) + c) * EDIM + (g << 3));
            f32x4 lo = *(const f32x4*)(src);
            f32x4 hi = *(const f32x4*)(src + 4);
            union { bf16x8 v; short s[8]; } f;
            f.s[0] = f2bf(lo[0]); f.s[1] = f2bf(lo[1]);
            f.s[2] = f2bf(lo[2]); f.s[3] = f2bf(lo[3]);
            f.s[4] = f2bf(hi[0]); f.s[5] = f2bf(hi[1]);
            f.s[6] = f2bf(hi[2]); f.s[7] = f2bf(hi[3]);
            a[e][q] = f.v;
        }
    }

    const int kt0 = (w << 2);
    // 3-deep rotating prefetch of tab fragments + wedge B-fragments
    f32x4 tn[3][4];
    bf16x8 bn[3];
    #pragma unroll
    for (int d = 0; d < 3; ++d) {
        bn[d] = *(const bf16x8*)(wedge_arr + ((d << 6) + lane) * 8);
        #pragma unroll
        for (int q = 0; q < 4; ++q)
            tn[d][q] = *(const f32x4*)(tab + ((((kt0 + q) << 4) + d) * 64 + lane) * 4);
    }

    const f32x4 zero4 = {0.f, 0.f, 0.f, 0.f};

    #pragma unroll
    for (int dt = 0; dt < 16; ++dt) {
        const int slot = dt % 3;           // compile-time after full unroll
        const bf16x8 bcur = bn[slot];
        f32x4 t0 = tn[slot][0], t1 = tn[slot][1],
              t2 = tn[slot][2], t3 = tn[slot][3];
        if (dt + 3 < 16) {
            bn[slot] = *(const bf16x8*)(wedge_arr + (((dt + 3) << 6) + lane) * 8);
            #pragma unroll
            for (int q = 0; q < 4; ++q)
                tn[slot][q] = *(const f32x4*)(tab +
                    ((((kt0 + q) << 4) + dt + 3) * 64 + lane) * 4);
        }
        float p[2] = {0.f, 0.f};
        #pragma unroll
        for (int e = 0; e < 2; ++e) {
            f32x4 cc;
            cc = __builtin_amdgcn_mfma_f32_16x16x32_bf16(a[e][0], bcur, zero4, 0, 0, 0);
            p[e] += cc[0] * t0[0] + cc[1] * t0[1] + cc[2] * t0[2] + cc[3] * t0[3];
            cc = __builtin_amdgcn_mfma_f32_16x16x32_bf16(a[e][1], bcur, zero4, 0, 0, 0);
            p[e] += cc[0] * t1[0] + cc[1] * t1[1] + cc[2] * t1[2] + cc[3] * t1[3];
            cc = __builtin_amdgcn_mfma_f32_16x16x32_bf16(a[e][2], bcur, zero4, 0, 0, 0);
            p[e] += cc[0] * t2[0] + cc[1] * t2[1] + cc[2] * t2[2] + cc[3] * t2[3];
            cc = __builtin_amdgcn_mfma_f32_16x16x32_bf16(a[e][3], bcur, zero4, 0, 0, 0);
            p[e] += cc[0] * t3[0] + cc[1] * t3[1] + cc[2] * t3[2] + cc[3] * t3[3];
        }
        #pragma unroll
        for (int e = 0; e < 2; ++e) {
            float v = p[e];
            v += __shfl_xor(v, 16, 64);
            v += __shfl_xor(v, 32, 64);
            if (lane < 16) part[w][e][(dt << 4) + lane] = v;
        }
    }
    __syncthreads();

    const float s1 = *s1p;
    for (int t = tid; t < 2 * 256; t += 256) {
        const int e = t >> 8;
        const int d = t & 255;
        const float s = part[0][e][d] + part[1][e][d] +
                        part[2][e][d] + part[3][e][d];
        agg[(size_t)(base + e) * DIM + d] = s * s1;
    }
}

// ---------------------------------------------------------------------------
// K2 out: gemm1+gemm2 tiled GEMM chain (identical to R6).
// ---------------------------------------------------------------------------
__global__ __launch_bounds__(512) void out_kernel(
    const short* __restrict__ elecb,
    const short* __restrict__ w1f, const short* __restrict__ w2f,
    const float* __restrict__ elec, const float* __restrict__ agg,
    const float* __restrict__ norm,
    const float* __restrict__ b1, const float* __restrict__ b2,
    const float* __restrict__ s2p,
    float* __restrict__ outp)
{
    __shared__ short h_s[16][264];      // +8 pad -> 2-way banks (free)

    const int tid  = threadIdx.x;
    const int w    = tid >> 6;          // 0..7
    const int lane = tid & 63;
    const int g    = lane >> 4;
    const int c    = lane & 15;
    const int mb   = blockIdx.x << 4;   // 16 rows per block

    const short* abase = elecb + ((mb + c) << 8) + (g << 3);
    bf16x8 a[8];
    #pragma unroll
    for (int q = 0; q < 8; ++q) a[q] = *(const bf16x8*)(abase + (q << 5));

    const float s2 = *s2p;

    // ---------------- gemm1 ----------------
    #pragma unroll
    for (int t = 0; t < 2; ++t) {
        const int ct = (w << 1) + t;
        const short* bb = w1f + (ct << 12) + (lane << 3);
        bf16x8 b[8];
        #pragma unroll
        for (int q = 0; q < 8; ++q) b[q] = *(const bf16x8*)(bb + (q << 9));
        f32x4 acc = {0.f, 0.f, 0.f, 0.f};
        #pragma unroll
        for (int q = 0; q < 8; ++q)
            acc = __builtin_amdgcn_mfma_f32_16x16x32_bf16(a[q], b[q], acc, 0, 0, 0);

        const int n  = (ct << 4) + c;
        const float bv = b1[n];
        #pragma unroll
        for (int r = 0; r < 4; ++r) {
            const int mr = (g << 2) + r;            // 0..15 (C-frag row)
            const int m  = mb + mr;
            const float y = (acc[r] + bv + agg[(m << 8) + n] * norm[m]) * s2;
            const float sig = 1.f / (1.f + __expf(-y));
            h_s[mr][n] = f2bf(GAIN_F * y * sig);
        }
    }
    __syncthreads();

    // ---------------- gemm2 ----------------
    bf16x8 a2[8];                                   // row = c, k = q*32+g*8+b
    #pragma unroll
    for (int q = 0; q < 8; ++q)
        a2[q] = *(const bf16x8*)(&h_s[c][(q << 5) + (g << 3)]);

    #pragma unroll
    for (int t = 0; t < 2; ++t) {
        const int ct = (w << 1) + t;
        const short* bb = w2f + (ct << 12) + (lane << 3);
        bf16x8 b[8];
        #pragma unroll
        for (int q = 0; q < 8; ++q) b[q] = *(const bf16x8*)(bb + (q << 9));
        f32x4 acc = {0.f, 0.f, 0.f, 0.f};
        #pragma unroll
        for (int q = 0; q < 8; ++q)
            acc = __builtin_amdgcn_mfma_f32_16x16x32_bf16(a2[q], b[q], acc, 0, 0, 0);

        const int n  = (ct << 4) + c;
        const float bv = b2[n];
        #pragma unroll
        for (int r = 0; r < 4; ++r) {
            const int m = mb + (g << 2) + r;
            const float z = acc[r] + bv;
            const float sig = 1.f / (1.f + __expf(-z));
            const float o = GAIN_F * z * sig;
            outp[(m << 8) + n] = (elec[(m << 8) + n] + o) * INV_SQRT2_F;
        }
    }
}

// ---------------------------------------------------------------------------
extern "C" void kernel_launch(void* const* d_in, const int* in_sizes, int n_in,
                              void* d_out, int out_size, void* d_ws, size_t ws_size,
                              hipStream_t stream)
{
    const float* elec  = (const float*)d_in[0];
    const float* up    = (const float*)d_in[1];
    const float* dn    = (const float*)d_in[2];
    const float* eemb  = (const float*)d_in[3];
    // d_in[4] = contr: init-time only, unused at runtime
    const float* norm  = (const float*)d_in[5];
    const float* W1    = (const float*)d_in[6];
    const float* b1    = (const float*)d_in[7];
    const float* Wedge = (const float*)d_in[8];
    const float* W2    = (const float*)d_in[9];
    const float* b2    = (const float*)d_in[10];
    const float* s1    = (const float*)d_in[11];
    const float* s2    = (const float*)d_in[12];

    // ws layout: tab_up 65536 f32 | tab_dn 65536 f32 | shorts:
    //   wedge_arr 8192 | w1f 65536 | w2f 65536 | elecb 262144 | agg (f32) 262144
    float* ws     = (float*)d_ws;
    float* tab_up = ws;
    float* tab_dn = ws + 65536;
    short* sbase  = (short*)(ws + 131072);
    short* warr   = sbase;
    short* w1f    = sbase + 8192;
    short* w2f    = sbase + 8192 + 65536;
    short* elecb  = sbase + 8192 + 131072;
    float* agg    = (float*)(sbase + 8192 + 131072 + 262144);

    prep_kernel<<<256, 256, 0, stream>>>(up, dn, Wedge, W1, W2, elec,
                                         tab_up, tab_dn, warr, w1f, w2f, elecb);
    edge_kernel<<<512, 256, 0, stream>>>(eemb, tab_up, tab_dn, warr, s1, agg);
    out_kernel <<<64, 512, 0, stream>>>(elecb, w1f, w2f, elec, agg, norm,
                                        b1, b2, s2, (float*)d_out);
}

// Round 9
// 31.236 us; speedup vs baseline: 2.1077x; 1.0350x over previous
//
#include <hip/hip_runtime.h>
#include <hip/hip_bf16.h>

// Sizes fixed by setup_inputs()
#define N_EL   1024
#define N_UP   512
#define NNUC   256
#define DIM    256
#define EDIM   32

#define GAIN_F      1.7872135f          // 1/std(silu(N(0,1))), analytic
#define INV_SQRT2_F 0.7071067811865476f

typedef __attribute__((ext_vector_type(8))) short bf16x8;
typedef __attribute__((ext_vector_type(4))) short bf16x4;
typedef __attribute__((ext_vector_type(4))) float f32x4;

__device__ __forceinline__ short f2bf(float x) {
    union { __hip_bfloat16 h; short s; } u;
    u.h = __float2bfloat16(x);     // compiler pk-fuses pairs (v_cvt_pk_bf16_f32)
    return u.s;
}

// ---------------------------------------------------------------------------
// K0 prep: layout rearrangement + f32->bf16 conversion (identical to R8).
// ---------------------------------------------------------------------------
__global__ __launch_bounds__(256) void prep_kernel(
    const float* __restrict__ up, const float* __restrict__ dn,
    const float* __restrict__ wedge,
    const float* __restrict__ w1, const float* __restrict__ w2,
    const float* __restrict__ elec,
    float* __restrict__ tab_up, float* __restrict__ tab_dn,
    short* __restrict__ wedge_arr,
    short* __restrict__ w1f, short* __restrict__ w2f,
    short* __restrict__ elecb)
{
    const int idx = (blockIdx.x << 8) + threadIdx.x;   // 0..65535

    { // spin tables -> C-fragment order (f32)
        const int kt = idx >> 12;
        const int dt = (idx >> 8) & 15;
        const int l  = (idx >> 2) & 63;
        const int r  = idx & 3;
        const int row = (kt << 4) + ((l >> 4) << 2) + r;
        const int col = (dt << 4) + (l & 15);
        tab_up[idx] = up[row * DIM + col];
        tab_dn[idx] = dn[row * DIM + col];
    }
    if (idx < 16 * 64 * 8) {                           // W_edge B-frag (8192)
        const int dt2 = idx >> 9;
        const int l2  = (idx >> 3) & 63;
        const int b   = idx & 7;
        const int j   = ((l2 >> 4) << 3) + b;
        const int d   = (dt2 << 4) + (l2 & 15);
        wedge_arr[idx] = f2bf(wedge[j * DIM + d]);
    }
    { // W1/W2 -> B-frag bf16 (65536 each)
        const int b  = idx & 7;
        const int l  = (idx >> 3) & 63;
        const int q  = (idx >> 9) & 7;
        const int nt = idx >> 12;
        const int j  = (q << 5) + ((l >> 4) << 3) + b;
        const int d  = (nt << 4) + (l & 15);
        w1f[idx] = f2bf(w1[j * DIM + d]);
        w2f[idx] = f2bf(w2[j * DIM + d]);
    }
    { // elec -> row-major bf16, 4 elems/thread
        const f32x4 v = *(const f32x4*)(elec + (idx << 2));
        bf16x4 o;
        o[0] = f2bf(v[0]); o[1] = f2bf(v[1]); o[2] = f2bf(v[2]); o[3] = f2bf(v[3]);
        *(bf16x4*)(elecb + (idx << 2)) = o;
    }
}

// ---------------------------------------------------------------------------
// K1 edge: 512 blocks x 2 electrons, 3-deep prefetch (identical to R8).
// ---------------------------------------------------------------------------
__global__ __launch_bounds__(256) void edge_kernel(
    const float* __restrict__ eemb,
    const float* __restrict__ tab_up, const float* __restrict__ tab_dn,
    const short* __restrict__ wedge_arr,
    const float* __restrict__ s1p,
    float* __restrict__ agg)
{
    __shared__ float part[4][2][256];      // [wave][e][d]  8 KB
    const int tid  = threadIdx.x;
    const int w    = tid >> 6;
    const int lane = tid & 63;
    const int g    = lane >> 4;
    const int c    = lane & 15;
    const int base = blockIdx.x << 1;      // 2 electrons per block
    const float* __restrict__ tab = (base < N_UP) ? tab_up : tab_dn;

    bf16x8 a[2][4];
    #pragma unroll
    for (int e = 0; e < 2; ++e) {
        #pragma unroll
        for (int q = 0; q < 4; ++q) {
            const int kt = (w << 2) + q;
            const float* src = eemb +
                ((size_t)((base + e) * NNUC + (kt << 4) + c) * EDIM + (g << 3));
            f32x4 lo = *(const f32x4*)(src);
            f32x4 hi = *(const f32x4*)(src + 4);
            union { bf16x8 v; short s[8]; } f;
            f.s[0] = f2bf(lo[0]); f.s[1] = f2bf(lo[1]);
            f.s[2] = f2bf(lo[2]); f.s[3] = f2bf(lo[3]);
            f.s[4] = f2bf(hi[0]); f.s[5] = f2bf(hi[1]);
            f.s[6] = f2bf(hi[2]); f.s[7] = f2bf(hi[3]);
            a[e][q] = f.v;
        }
    }

    const int kt0 = (w << 2);
    f32x4 tn[3][4];
    bf16x8 bn[3];
    #pragma unroll
    for (int d = 0; d < 3; ++d) {
        bn[d] = *(const bf16x8*)(wedge_arr + ((d << 6) + lane) * 8);
        #pragma unroll
        for (int q = 0; q < 4; ++q)
            tn[d][q] = *(const f32x4*)(tab + ((((kt0 + q) << 4) + d) * 64 + lane) * 4);
    }

    const f32x4 zero4 = {0.f, 0.f, 0.f, 0.f};

    #pragma unroll
    for (int dt = 0; dt < 16; ++dt) {
        const int slot = dt % 3;           // compile-time after full unroll
        const bf16x8 bcur = bn[slot];
        f32x4 t0 = tn[slot][0], t1 = tn[slot][1],
              t2 = tn[slot][2], t3 = tn[slot][3];
        if (dt + 3 < 16) {
            bn[slot] = *(const bf16x8*)(wedge_arr + (((dt + 3) << 6) + lane) * 8);
            #pragma unroll
            for (int q = 0; q < 4; ++q)
                tn[slot][q] = *(const f32x4*)(tab +
                    ((((kt0 + q) << 4) + dt + 3) * 64 + lane) * 4);
        }
        float p[2] = {0.f, 0.f};
        #pragma unroll
        for (int e = 0; e < 2; ++e) {
            f32x4 cc;
            cc = __builtin_amdgcn_mfma_f32_16x16x32_bf16(a[e][0], bcur, zero4, 0, 0, 0);
            p[e] += cc[0] * t0[0] + cc[1] * t0[1] + cc[2] * t0[2] + cc[3] * t0[3];
            cc = __builtin_amdgcn_mfma_f32_16x16x32_bf16(a[e][1], bcur, zero4, 0, 0, 0);
            p[e] += cc[0] * t1[0] + cc[1] * t1[1] + cc[2] * t1[2] + cc[3] * t1[3];
            cc = __builtin_amdgcn_mfma_f32_16x16x32_bf16(a[e][2], bcur, zero4, 0, 0, 0);
            p[e] += cc[0] * t2[0] + cc[1] * t2[1] + cc[2] * t2[2] + cc[3] * t2[3];
            cc = __builtin_amdgcn_mfma_f32_16x16x32_bf16(a[e][3], bcur, zero4, 0, 0, 0);
            p[e] += cc[0] * t3[0] + cc[1] * t3[1] + cc[2] * t3[2] + cc[3] * t3[3];
        }
        #pragma unroll
        for (int e = 0; e < 2; ++e) {
            float v = p[e];
            v += __shfl_xor(v, 16, 64);
            v += __shfl_xor(v, 32, 64);
            if (lane < 16) part[w][e][(dt << 4) + lane] = v;
        }
    }
    __syncthreads();

    const float s1 = *s1p;
    for (int t = tid; t < 2 * 256; t += 256) {
        const int e = t >> 8;
        const int d = t & 255;
        const float s = part[0][e][d] + part[1][e][d] +
                        part[2][e][d] + part[3][e][d];
        agg[(size_t)(base + e) * DIM + d] = s * s1;
    }
}

// ---------------------------------------------------------------------------
// K2 out v2: 256 blocks (64 row-tiles x 4 quadrants) x 512 threads.
// gemm1 is computed REDUNDANTLY per quadrant (R6 code verbatim, h -> LDS);
// gemm2: waves 0..3 each compute one col-tile of this block's quadrant.
// 4x CU coverage vs R6's 64-block version; each output col written once.
// ---------------------------------------------------------------------------
__global__ __launch_bounds__(512) void out_kernel(
    const short* __restrict__ elecb,
    const short* __restrict__ w1f, const short* __restrict__ w2f,
    const float* __restrict__ elec, const float* __restrict__ agg,
    const float* __restrict__ norm,
    const float* __restrict__ b1, const float* __restrict__ b2,
    const float* __restrict__ s2p,
    float* __restrict__ outp)
{
    __shared__ short h_s[16][264];      // +8 pad -> 2-way banks (free)

    const int tid  = threadIdx.x;
    const int w    = tid >> 6;          // 0..7
    const int lane = tid & 63;
    const int g    = lane >> 4;
    const int c    = lane & 15;
    const int mt   = blockIdx.x >> 2;   // row-tile 0..63
    const int qd   = blockIdx.x & 3;    // quadrant 0..3
    const int mb   = mt << 4;           // 16 rows per row-tile

    const short* abase = elecb + ((mb + c) << 8) + (g << 3);
    bf16x8 a[8];
    #pragma unroll
    for (int q = 0; q < 8; ++q) a[q] = *(const bf16x8*)(abase + (q << 5));

    const float s2 = *s2p;

    // ---------------- gemm1 (all 16 col-tiles; identical to R6) ----------------
    #pragma unroll
    for (int t = 0; t < 2; ++t) {
        const int ct = (w << 1) + t;
        const short* bb = w1f + (ct << 12) + (lane << 3);
        bf16x8 b[8];
        #pragma unroll
        for (int q = 0; q < 8; ++q) b[q] = *(const bf16x8*)(bb + (q << 9));
        f32x4 acc = {0.f, 0.f, 0.f, 0.f};
        #pragma unroll
        for (int q = 0; q < 8; ++q)
            acc = __builtin_amdgcn_mfma_f32_16x16x32_bf16(a[q], b[q], acc, 0, 0, 0);

        const int n  = (ct << 4) + c;
        const float bv = b1[n];
        #pragma unroll
        for (int r = 0; r < 4; ++r) {
            const int mr = (g << 2) + r;            // 0..15 (C-frag row)
            const int m  = mb + mr;
            const float y = (acc[r] + bv + agg[(m << 8) + n] * norm[m]) * s2;
            const float sig = 1.f / (1.f + __expf(-y));
            h_s[mr][n] = f2bf(GAIN_F * y * sig);
        }
    }
    __syncthreads();

    // ---------------- gemm2 (this block's quadrant only; waves 0..3) ----------
    if (w < 4) {
        bf16x8 a2[8];                               // row = c, k = q*32+g*8+b
        #pragma unroll
        for (int q = 0; q < 8; ++q)
            a2[q] = *(const bf16x8*)(&h_s[c][(q << 5) + (g << 3)]);

        const int ct = (qd << 2) + w;               // col-tile 0..15, unique/chip
        const short* bb = w2f + (ct << 12) + (lane << 3);
        bf16x8 b[8];
        #pragma unroll
        for (int q = 0; q < 8; ++q) b[q] = *(const bf16x8*)(bb + (q << 9));
        f32x4 acc = {0.f, 0.f, 0.f, 0.f};
        #pragma unroll
        for (int q = 0; q < 8; ++q)
            acc = __builtin_amdgcn_mfma_f32_16x16x32_bf16(a2[q], b[q], acc, 0, 0, 0);

        const int n  = (ct << 4) + c;
        const float bv = b2[n];
        #pragma unroll
        for (int r = 0; r < 4; ++r) {
            const int m = mb + (g << 2) + r;
            const float z = acc[r] + bv;
            const float sig = 1.f / (1.f + __expf(-z));
            const float o = GAIN_F * z * sig;
            outp[(m << 8) + n] = (elec[(m << 8) + n] + o) * INV_SQRT2_F;
        }
    }
}

// ---------------------------------------------------------------------------
extern "C" void kernel_launch(void* const* d_in, const int* in_sizes, int n_in,
                              void* d_out, int out_size, void* d_ws, size_t ws_size,
                              hipStream_t stream)
{
    const float* elec  = (const float*)d_in[0];
    const float* up    = (const float*)d_in[1];
    const float* dn    = (const float*)d_in[2];
    const float* eemb  = (const float*)d_in[3];
    // d_in[4] = contr: init-time only, unused at runtime
    const float* norm  = (const float*)d_in[5];
    const float* W1    = (const float*)d_in[6];
    const float* b1    = (const float*)d_in[7];
    const float* Wedge = (const float*)d_in[8];
    const float* W2    = (const float*)d_in[9];
    const float* b2    = (const float*)d_in[10];
    const float* s1    = (const float*)d_in[11];
    const float* s2    = (const float*)d_in[12];

    // ws layout: tab_up 65536 f32 | tab_dn 65536 f32 | shorts:
    //   wedge_arr 8192 | w1f 65536 | w2f 65536 | elecb 262144 | agg (f32) 262144
    float* ws     = (float*)d_ws;
    float* tab_up = ws;
    float* tab_dn = ws + 65536;
    short* sbase  = (short*)(ws + 131072);
    short* warr   = sbase;
    short* w1f    = sbase + 8192;
    short* w2f    = sbase + 8192 + 65536;
    short* elecb  = sbase + 8192 + 131072;
    float* agg    = (float*)(sbase + 8192 + 131072 + 262144);

    prep_kernel<<<256, 256, 0, stream>>>(up, dn, Wedge, W1, W2, elec,
                                         tab_up, tab_dn, warr, w1f, w2f, elecb);
    edge_kernel<<<512, 256, 0, stream>>>(eemb, tab_up, tab_dn, warr, s1, agg);
    out_kernel <<<256, 512, 0, stream>>>(elecb, w1f, w2f, elec, agg, norm,
                                         b1, b2, s2, (float*)d_out);
}